// Round 3
// baseline (311.518 us; speedup 1.0000x reference)
//
#include <hip/hip_runtime.h>

// NonLocalBlock: B=2, C=256, N=D*H*W=6272, mid=128.
// R2: key-split flash-decode attention. Grid (N/64, KSPLIT=4, B), 4-wave
// blocks (qh x kh quadrants of a 64q x 64k tile). 12 resident waves/CU
// (R1 had 3). Each block emits a normalized f16 partial O + (m,l); epi
// merges the 4 splits on the fly, then does the w4 GEMM + residual.

#define BB  2
#define CC  256
#define NN  6272
#define MID 128
#define KSPLIT 4

typedef _Float16 half4_t __attribute__((ext_vector_type(4)));
typedef _Float16 half8_t __attribute__((ext_vector_type(8)));
typedef float    floatx16 __attribute__((ext_vector_type(16)));

__device__ __forceinline__ void fma4(float4& a, const float4 v, const float s) {
    a.x += v.x * s; a.y += v.y * s; a.z += v.z * s; a.w += v.w * s;
}
__device__ __forceinline__ float dot4(const float4 a, const float4 b) {
    return a.x * b.x + a.y * b.y + a.z * b.z + a.w * b.w;
}

// ---------------------------------------------------------------------------
// Projection: e_pj[n][m] = dot(w_pj[m,:], x[b,:,n]) + bias.
// pj 0 -> Qg f16 [b][n][128]; pj 1 -> Kg f16 [b][n][128]; pj 2 -> VtG f16 [b][128][n].
// grid (NN/64, 3, BB), block 256.
// ---------------------------------------------------------------------------
__global__ __launch_bounds__(256, 2) void proj_kernel(
    const float* __restrict__ x,
    const float* __restrict__ w1, const float* __restrict__ bi1,
    const float* __restrict__ w2, const float* __restrict__ bi2,
    const float* __restrict__ w3, const float* __restrict__ bi3,
    _Float16* __restrict__ Qg, _Float16* __restrict__ Kg, _Float16* __restrict__ VtG)
{
    const int t  = threadIdx.x;
    const int n0 = blockIdx.x * 64;
    const int pj = blockIdx.y;
    const int b  = blockIdx.z;
    const float* w  = (pj == 0) ? w1 : (pj == 1) ? w2 : w3;
    const float* bi = (pj == 0) ? bi1 : (pj == 1) ? bi2 : bi3;

    __shared__ float xs[CC * 68];
    {
        const float* xb = x + (size_t)b * CC * NN;
        for (int r = t; r < CC * 16; r += 256) {
            int c = r >> 4, j = (r & 15) << 2;
            float4 v = *(const float4*)(xb + (size_t)c * NN + n0 + j);
            *(float4*)&xs[c * 68 + j] = v;
        }
    }
    __syncthreads();

    const int n4 = (t & 15) << 2;   // 4 consecutive n per thread
    const int m0 = (t >> 4) << 3;   // 8 m-rows per thread
    float4 acc4[8];
    #pragma unroll
    for (int k = 0; k < 8; ++k) acc4[k] = make_float4(0.f, 0.f, 0.f, 0.f);

    for (int cc = 0; cc < CC; cc += 4) {
        float4 xv[4];
        #pragma unroll
        for (int u = 0; u < 4; ++u)
            xv[u] = *(const float4*)&xs[(cc + u) * 68 + n4];
        #pragma unroll
        for (int k = 0; k < 8; ++k) {
            float4 wq = *(const float4*)(w + (size_t)(m0 + k) * CC + cc);
            fma4(acc4[k], xv[0], wq.x);
            fma4(acc4[k], xv[1], wq.y);
            fma4(acc4[k], xv[2], wq.z);
            fma4(acc4[k], xv[3], wq.w);
        }
    }

    const float* af = (const float*)acc4;   // af[k*4 + i], i = n-sub, k = m-sub
    float bb[8];
    #pragma unroll
    for (int k = 0; k < 8; ++k) bb[k] = bi[m0 + k];

    if (pj < 2) {
        _Float16* eo = ((pj == 0) ? Qg : Kg) + (size_t)b * NN * MID;
        #pragma unroll
        for (int i = 0; i < 4; ++i) {
            half8_t h;
            #pragma unroll
            for (int k = 0; k < 8; ++k) h[k] = (_Float16)(af[k * 4 + i] + bb[k]);
            *(half8_t*)(eo + (size_t)(n0 + n4 + i) * MID + m0) = h;
        }
    } else {
        _Float16* eo = VtG + (size_t)b * MID * NN;
        #pragma unroll
        for (int k = 0; k < 8; ++k) {
            half4_t h;
            #pragma unroll
            for (int i = 0; i < 4; ++i) h[i] = (_Float16)(af[k * 4 + i] + bb[k]);
            *(half4_t*)(eo + (size_t)(m0 + k) * NN + n0 + n4) = h;
        }
    }
}

// ---------------------------------------------------------------------------
// Flash attention, f16 MFMA, key-split. grid (NN/64, KSPLIT, BB), block 256.
// Wave = (qh, kh): q-half (32 q's) x k'-half (32 of 64 tile keys).
// Each wave keeps private (m,l,O); kh-halves merged in LDS at the end;
// block stores normalized f16 partial + (m,l) for its key split.
// LDS (46208 B, 3 blocks/CU):
//   Ks [64][136] f16 (17408) | Vt [128][72] f16 (18432) | Pt [64][72] f16 (9216)
//   msh/lsh [2][72] f32 (1152). Obuf [64][132] f32 aliases Ks/Vt at the end.
// ---------------------------------------------------------------------------
__global__ __launch_bounds__(256, 3) void attn_kernel(
    const _Float16* __restrict__ Qg, const _Float16* __restrict__ Kg,
    const _Float16* __restrict__ VtG, _Float16* __restrict__ Opart,
    float* __restrict__ Mst, float* __restrict__ Lst)
{
    const int t    = threadIdx.x;
    const int lane = t & 63;
    const int wave = t >> 6;
    const int qh   = wave & 1;
    const int kh   = wave >> 1;
    const int l31  = lane & 31;
    const int l5   = lane >> 5;
    const int q0   = blockIdx.x * 64;
    const int split= blockIdx.y;
    const int b    = blockIdx.z;

    // key tiles [t0, t0+tcnt) of 98 total: 25,25,24,24
    const int t0   = split * 24 + (split < 2 ? split : 2);
    const int tcnt = (split < 2) ? 25 : 24;

    __shared__ __align__(16) char lds[46208];
    _Float16* Ks = (_Float16*)lds;                        // 64*136
    _Float16* Vt = (_Float16*)(lds + 17408);              // 128*72
    _Float16* Pt = (_Float16*)(lds + 35840);              // 64*72
    float* msh   = (float*)(lds + 45056);                 // [2][72]
    float* lsh   = msh + 144;                             // [2][72]
    float* Obuf  = (float*)lds;                           // 64*132 f32 (alias)

    const _Float16* Qb = Qg + ((size_t)b * NN + q0 + qh * 32) * MID;
    const _Float16* Kb = Kg + (size_t)b * NN * MID;
    const _Float16* Vb = VtG + (size_t)b * MID * NN;

    // Q B-frags, loop-invariant: lane holds Q[q0+qh*32+l31][ds*16 + l5*8 + j]
    half8_t qf[8];
    #pragma unroll
    for (int ds = 0; ds < 8; ++ds)
        qf[ds] = *(const half8_t*)(Qb + (size_t)l31 * MID + ds * 16 + l5 * 8);

    floatx16 o[4];
    #pragma unroll
    for (int dt = 0; dt < 4; ++dt)
        #pragma unroll
        for (int j = 0; j < 16; ++j) o[dt][j] = 0.f;
    float m_run = -3.0e38f, l_run = 0.f;

    for (int kt = t0; kt < t0 + tcnt; ++kt) {
        const int nk = kt * 64;
        // ---- stage K [64][136] and V^T [128][72] (256 threads) ----
        #pragma unroll
        for (int it = 0; it < 4; ++it) {
            int c = it * 256 + t;
            int r = c >> 4, off = (c & 15) * 8;
            *(half8_t*)(Ks + r * 136 + off) =
                *(const half8_t*)(Kb + (size_t)(nk + r) * MID + off);
        }
        #pragma unroll
        for (int it = 0; it < 4; ++it) {
            int c = it * 256 + t;
            int d = c >> 3, off = (c & 7) * 8;
            *(half8_t*)(Vt + d * 72 + off) =
                *(const half8_t*)(Vb + (size_t)d * NN + nk + off);
        }
        __syncthreads();

        // ---- S^T = K . Q^T over this wave's 32-k' strip ----
        floatx16 s;
        #pragma unroll
        for (int j = 0; j < 16; ++j) s[j] = 0.f;
        const _Float16* krow = Ks + (kh * 32 + l31) * 136 + l5 * 8;
        #pragma unroll
        for (int ds = 0; ds < 8; ++ds)
            s = __builtin_amdgcn_mfma_f32_32x32x16_f16(
                    *(const half8_t*)(krow + ds * 16), qf[ds], s, 0, 0, 0);

        // ---- online softmax (lane pair l31 / l31+32 shares q column) ----
        float tmax = s[0];
        #pragma unroll
        for (int j = 1; j < 16; ++j) tmax = fmaxf(tmax, s[j]);
        tmax = fmaxf(tmax, __shfl_xor(tmax, 32));
        const float m_new = fmaxf(m_run, tmax);
        const float alpha = __expf(m_run - m_new);
        m_run = m_new;

        float psum = 0.f;
        _Float16* prow = Pt + (qh * 32 + l31) * 72 + kh * 32 + 4 * l5;
        #pragma unroll
        for (int g = 0; g < 4; ++g) {
            float p0 = __expf(s[4 * g + 0] - m_new);
            float p1 = __expf(s[4 * g + 1] - m_new);
            float p2 = __expf(s[4 * g + 2] - m_new);
            float p3 = __expf(s[4 * g + 3] - m_new);
            psum += (p0 + p1) + (p2 + p3);
            half4_t h;
            h[0] = (_Float16)p0; h[1] = (_Float16)p1;
            h[2] = (_Float16)p2; h[3] = (_Float16)p3;
            *(half4_t*)(prow + 8 * g) = h;   // k' = kh*32 + 8g + 4*l5 + {0..3}
        }
        psum += __shfl_xor(psum, 32);
        l_run = l_run * alpha + psum;

        #pragma unroll
        for (int dt = 0; dt < 4; ++dt)
            #pragma unroll
            for (int j = 0; j < 16; ++j) o[dt][j] *= alpha;

        // Pt quadrant is wave-private; only in-wave cross-lane dep -> drain lgkm.
        __builtin_amdgcn_s_waitcnt(0xC07F);

        // ---- O^T += V^T . P^T over this wave's k'-strip (own q-half) ----
        #pragma unroll
        for (int ks = 0; ks < 2; ++ks) {
            half8_t pf = *(const half8_t*)(Pt + (qh * 32 + l31) * 72 +
                                           kh * 32 + ks * 16 + l5 * 8);
            const _Float16* vcol = Vt + kh * 32 + ks * 16 + l5 * 8;
            #pragma unroll
            for (int dt = 0; dt < 4; ++dt)
                o[dt] = __builtin_amdgcn_mfma_f32_32x32x16_f16(
                            *(const half8_t*)(vcol + (dt * 32 + l31) * 72), pf,
                            o[dt], 0, 0, 0);
        }
        __syncthreads();
    }

    // ---- merge kh-halves, normalize, store f16 partial + stats ----
    const int qm = qh * 32 + l31;
    if (l5 == 0) { msh[kh * 72 + qm] = m_run; lsh[kh * 72 + qm] = l_run; }
    __syncthreads();
    const float m0v = msh[qm], m1v = msh[72 + qm];
    const float M   = fmaxf(m0v, m1v);
    const float Lt  = lsh[qm] * __expf(m0v - M) + lsh[72 + qm] * __expf(m1v - M);
    const float sc  = __expf(m_run - M) / Lt;

    if (kh == 0) {
        #pragma unroll
        for (int dt = 0; dt < 4; ++dt)
            #pragma unroll
            for (int j = 0; j < 16; ++j) {
                int d = dt * 32 + (j & 3) + 8 * (j >> 2) + 4 * l5;
                Obuf[qm * 132 + d] = o[dt][j] * sc;
            }
    }
    __syncthreads();
    if (kh == 1) {
        #pragma unroll
        for (int dt = 0; dt < 4; ++dt)
            #pragma unroll
            for (int j = 0; j < 16; ++j) {
                int d = dt * 32 + (j & 3) + 8 * (j >> 2) + 4 * l5;
                Obuf[qm * 132 + d] += o[dt][j] * sc;
            }
    }
    __syncthreads();

    _Float16* Ob = Opart + ((size_t)(b * KSPLIT + split) * NN + q0) * MID;
    #pragma unroll
    for (int it = 0; it < 4; ++it) {
        int c = it * 256 + t;
        int q = c >> 4, off = (c & 15) * 8;
        half8_t h;
        #pragma unroll
        for (int j = 0; j < 8; ++j) h[j] = (_Float16)Obuf[q * 132 + off + j];
        *(half8_t*)(Ob + (size_t)q * MID + off) = h;
    }
    if (t < 64) {
        const float a0 = msh[t], a1 = msh[72 + t];
        const float MM = fmaxf(a0, a1);
        const float LL = lsh[t] * __expf(a0 - MM) + lsh[72 + t] * __expf(a1 - MM);
        const size_t idx = (size_t)(b * KSPLIT + split) * NN + q0 + t;
        Mst[idx] = MM;
        Lst[idx] = LL;
    }
}

// ---------------------------------------------------------------------------
// Epilogue + split merge: out[b][c][n] = x + w4 @ (merged attn)^T + b4.
// grid (NN/32, 2, BB) block 256: 32 n x 128 c per block.
// ---------------------------------------------------------------------------
__global__ __launch_bounds__(256, 2) void epi_kernel(
    const _Float16* __restrict__ Opart, const float* __restrict__ Mst,
    const float* __restrict__ Lst, const float* __restrict__ w4,
    const float* __restrict__ b4, const float* __restrict__ x,
    float* __restrict__ out)
{
    const int t  = threadIdx.x;
    const int n0 = blockIdx.x * 32;
    const int ch = blockIdx.y;      // c-half
    const int b  = blockIdx.z;

    __shared__ float as[32 * 132];
    __shared__ float wts[KSPLIT][36];

    if (t < 32) {
        float m[KSPLIT], l[KSPLIT];
        #pragma unroll
        for (int s = 0; s < KSPLIT; ++s) {
            const size_t idx = (size_t)(b * KSPLIT + s) * NN + n0 + t;
            m[s] = Mst[idx]; l[s] = Lst[idx];
        }
        float M = m[0];
        #pragma unroll
        for (int s = 1; s < KSPLIT; ++s) M = fmaxf(M, m[s]);
        float L = 0.f, wl[KSPLIT];
        #pragma unroll
        for (int s = 0; s < KSPLIT; ++s) { wl[s] = l[s] * __expf(m[s] - M); L += wl[s]; }
        const float inv = 1.0f / L;
        #pragma unroll
        for (int s = 0; s < KSPLIT; ++s) wts[s][t] = wl[s] * inv;
    }
    __syncthreads();

    // merge splits into the fp32 LDS tile
    for (int r = t; r < 32 * 16; r += 256) {
        int q = r >> 4, off = (r & 15) * 8;
        float acc[8];
        #pragma unroll
        for (int j = 0; j < 8; ++j) acc[j] = 0.f;
        #pragma unroll
        for (int s = 0; s < KSPLIT; ++s) {
            const float wv = wts[s][q];
            half8_t h = *(const half8_t*)(Opart +
                ((size_t)(b * KSPLIT + s) * NN + n0 + q) * MID + off);
            #pragma unroll
            for (int j = 0; j < 8; ++j) acc[j] += wv * (float)h[j];
        }
        *(float4*)&as[q * 132 + off]     = make_float4(acc[0], acc[1], acc[2], acc[3]);
        *(float4*)&as[q * 132 + off + 4] = make_float4(acc[4], acc[5], acc[6], acc[7]);
    }
    __syncthreads();

    const int n4 = (t & 7) << 2;            // 4 n's
    const int c0 = ch * 128 + (t >> 3) * 4; // 4 c's
    float4 accE[4];
    #pragma unroll
    for (int k = 0; k < 4; ++k) accE[k] = make_float4(0.f, 0.f, 0.f, 0.f);

    for (int ms = 0; ms < 32; ++ms) {
        float4 av[4];
        #pragma unroll
        for (int i = 0; i < 4; ++i)
            av[i] = *(const float4*)&as[(n4 + i) * 132 + (ms << 2)];
        #pragma unroll
        for (int k = 0; k < 4; ++k) {
            float4 wq = *(const float4*)(w4 + (size_t)(c0 + k) * MID + (ms << 2));
            accE[k].x += dot4(av[0], wq);
            accE[k].y += dot4(av[1], wq);
            accE[k].z += dot4(av[2], wq);
            accE[k].w += dot4(av[3], wq);
        }
    }

    #pragma unroll
    for (int k = 0; k < 4; ++k) {
        const int c = c0 + k;
        const float bv = b4[c];
        const size_t off = ((size_t)b * CC + c) * NN + n0 + n4;
        float4 xr = *(const float4*)(x + off);
        float4 r;
        r.x = accE[k].x + bv + xr.x;
        r.y = accE[k].y + bv + xr.y;
        r.z = accE[k].z + bv + xr.z;
        r.w = accE[k].w + bv + xr.w;
        *(float4*)(out + off) = r;
    }
}

extern "C" void kernel_launch(void* const* d_in, const int* in_sizes, int n_in,
                              void* d_out, int out_size, void* d_ws, size_t ws_size,
                              hipStream_t stream)
{
    const float* x  = (const float*)d_in[0];
    const float* w1 = (const float*)d_in[1];
    const float* b1 = (const float*)d_in[2];
    const float* w2 = (const float*)d_in[3];
    const float* b2 = (const float*)d_in[4];
    const float* w3 = (const float*)d_in[5];
    const float* b3 = (const float*)d_in[6];
    const float* w4 = (const float*)d_in[7];
    const float* b4 = (const float*)d_in[8];
    float* out = (float*)d_out;

    // ws: Qg|Kg f16 [B][N][128], VtG f16 [B][128][N], Opart f16 [B][KSPLIT][N][128],
    //     Mst|Lst f32 [B][KSPLIT][N]   (~22.9 MB total)
    _Float16* Qg    = (_Float16*)d_ws;
    _Float16* Kg    = Qg + (size_t)BB * NN * MID;
    _Float16* VtG   = Kg + (size_t)BB * NN * MID;
    _Float16* Opart = VtG + (size_t)BB * NN * MID;
    float*    Mst   = (float*)(Opart + (size_t)BB * KSPLIT * NN * MID);
    float*    Lst   = Mst + (size_t)BB * KSPLIT * NN;

    proj_kernel<<<dim3(NN / 64, 3, BB), 256, 0, stream>>>(x, w1, b1, w2, b2, w3, b3, Qg, Kg, VtG);
    attn_kernel<<<dim3(NN / 64, KSPLIT, BB), 256, 0, stream>>>(Qg, Kg, VtG, Opart, Mst, Lst);
    epi_kernel<<<dim3(NN / 32, 2, BB), 256, 0, stream>>>(Opart, Mst, Lst, w4, b4, x, out);
}